// Round 22
// baseline (273.645 us; speedup 1.0000x reference)
//
#include <hip/hip_runtime.h>
#include <hip/hip_bf16.h>

typedef __bf16 bf16;
typedef __bf16 bf16x4 __attribute__((ext_vector_type(4)));
typedef __bf16 bf16x8 __attribute__((ext_vector_type(8)));
typedef float f32x4 __attribute__((ext_vector_type(4)));
typedef float f32x16 __attribute__((ext_vector_type(16)));
typedef unsigned u32x4 __attribute__((ext_vector_type(4)));

#define MFMA16(a, b, c) __builtin_amdgcn_mfma_f32_16x16x32_bf16((a), (b), (c), 0, 0, 0)
#define MFMA32(a, b, c) __builtin_amdgcn_mfma_f32_32x32x16_bf16((a), (b), (c), 0, 0, 0)

// XCD-chunked block swizzle (nblk % 8 == 0): each XCD gets a contiguous chunk.
__device__ __forceinline__ int xcd_swizzle(int bid, int nblk) {
  const int per = nblk >> 3;
  return (bid & 7) * per + (bid >> 3);
}

__device__ __forceinline__ void gload_lds16(const bf16* g, bf16* lds) {
  __builtin_amdgcn_global_load_lds(
      (const __attribute__((address_space(1))) void*)g,
      (__attribute__((address_space(3))) void*)lds, 16, 0, 0);
}

// Raw hardware exp2 (1 trans instr). Verified correct r18-r21.
__device__ __forceinline__ float fast_exp2(float x) {
  float r;
  asm("v_exp_f32 %0, %1\n\ts_nop 1" : "=v"(r) : "v"(x));
  return r;
}

// Packed f32x2 -> bf16x2 convert (1 instr). Verified correct r18-r21.
__device__ __forceinline__ unsigned cvt_pk_bf16(float lo, float hi) {
  unsigned r;
  asm("v_cvt_pk_bf16_f32 %0, %1, %2" : "=v"(r) : "v"(lo), "v"(hi));
  return r;
}

// ---------------- GEMM machinery (128x128 tile, BK=32, 1-barrier) ----------
// BK 64->32: LDS 64KB->32KB -> 4 blocks/CU (was 2; r21 showed both GEMMs at
// ~20% occupancy with all pipes <20% = serial chains with no co-resident
// waves to overlap).
template <typename T> struct StageRegs;
template <> struct StageRegs<float> { float4 lo[2], hi[2]; };
template <> struct StageRegs<bf16> { bf16x8 v[2]; };

template <typename T>
__device__ __forceinline__ void stage_issue(StageRegs<T>& r, const T* base,
                                            int brc, int k0, int tid) {
#pragma unroll
  for (int i = 0; i < 2; ++i) {
    const int c = i * 256 + tid;     // 512 chunks of 8 elems = 128x32
    const int row = c >> 2, lin = c & 3;
    const T* p = base + (size_t)(brc + row) * 1024 + k0 + lin * 8;
    if constexpr (sizeof(T) == 4) {
      r.lo[i] = *reinterpret_cast<const float4*>(p);
      r.hi[i] = *reinterpret_cast<const float4*>(p + 4);
    } else {
      r.v[i] = *reinterpret_cast<const bf16x8*>(p);
    }
  }
}

template <typename T>
__device__ __forceinline__ void stage_write(const StageRegs<T>& r, bf16* sm,
                                            int tid) {
#pragma unroll
  for (int i = 0; i < 2; ++i) {
    const int c = i * 256 + tid;
    const int row = c >> 2, lin = c & 3;
    const int slot = lin ^ (row & 3);
    if constexpr (sizeof(T) == 4) {
      const float4 a = r.lo[i], b = r.hi[i];
      u32x4 w;
      w[0] = cvt_pk_bf16(a.x, a.y);
      w[1] = cvt_pk_bf16(a.z, a.w);
      w[2] = cvt_pk_bf16(b.x, b.y);
      w[3] = cvt_pk_bf16(b.z, b.w);
      *reinterpret_cast<u32x4*>(sm + row * 32 + slot * 8) = w;
    } else {
      *reinterpret_cast<bf16x8*>(sm + row * 32 + slot * 8) = r.v[i];
    }
  }
}

// Main loop: 32 K-tiles of 32; ONE barrier/tile; stage_issue(t+1) after the
// barrier so loads fly under compute(t). Race-safe (r20/r21 verified form).
template <typename TA>
__device__ __forceinline__ void gemm_core(const TA* A, const float* W,
                                          int brow, int bcol, int tid, int wm,
                                          int wn, int l15, int l4,
                                          bf16 (*Asm)[4096], bf16 (*Bsm)[4096],
                                          f32x4 (&acc)[4][4]) {
  StageRegs<TA> ra;
  StageRegs<float> rb;
  stage_issue(ra, A, brow, 0, tid);
  stage_issue(rb, W, bcol, 0, tid);
  int p = 0;
  for (int t = 0; t < 32; ++t) {
    stage_write(ra, Asm[p], tid);   // compiler waits vmcnt for ra/rb here
    stage_write(rb, Bsm[p], tid);
    __syncthreads();                // publish buffer p
    if (t + 1 < 32) {
      stage_issue(ra, A, brow, (t + 1) << 5, tid);  // fly under compute
      stage_issue(rb, W, bcol, (t + 1) << 5, tid);
    }
    bf16x8 af[4], bfr[4];
#pragma unroll
    for (int m = 0; m < 4; ++m) {
      const int row = wm + m * 16 + l15;
      const int slot = l4 ^ (row & 3);
      af[m] = *reinterpret_cast<const bf16x8*>(Asm[p] + row * 32 + slot * 8);
    }
#pragma unroll
    for (int n = 0; n < 4; ++n) {
      const int row = wn + n * 16 + l15;
      const int slot = l4 ^ (row & 3);
      bfr[n] = *reinterpret_cast<const bf16x8*>(Bsm[p] + row * 32 + slot * 8);
    }
    __builtin_amdgcn_s_setprio(1);
#pragma unroll
    for (int m = 0; m < 4; ++m)
#pragma unroll
      for (int n = 0; n < 4; ++n)
        acc[m][n] = MFMA16(af[m], bfr[n], acc[m][n]);
    __builtin_amdgcn_s_setprio(0);
    p ^= 1;
  }
}

// Fused QKV projection. seg 0 -> Qws (x log2e/8), seg 1 -> Kws,
// seg 2 -> Vt written TRANSPOSED.
__global__ __launch_bounds__(256, 2) void qkv_gemm_kernel(
    const float* __restrict__ query, const float* __restrict__ key,
    const float* __restrict__ value, const float* __restrict__ wq,
    const float* __restrict__ wk, const float* __restrict__ wv,
    const float* __restrict__ bq, const float* __restrict__ bk,
    const float* __restrict__ bv, bf16* __restrict__ Qws,
    bf16* __restrict__ Kws, bf16* __restrict__ Vt, float qscale) {
  __shared__ bf16 Asm[2][128 * 32];
  __shared__ bf16 Bsm[2][128 * 32];
  const int tid = threadIdx.x;
  const int lane = tid & 63;
  const int wid = tid >> 6;
  const int l15 = lane & 15;
  const int l4 = lane >> 4;
  const int bid = xcd_swizzle(blockIdx.x, 1536);
  const int seg = bid / 512;
  const int inner = bid % 512;
  const int brow = (inner >> 3) << 7;
  const int bcol = (inner & 7) << 7;
  const int wm = (wid >> 1) << 6;
  const int wn = (wid & 1) << 6;

  const float* A = seg == 0 ? query : (seg == 1 ? key : value);
  const float* W = seg == 0 ? wq : (seg == 1 ? wk : wv);
  const float* bias = seg == 0 ? bq : (seg == 1 ? bk : bv);

  f32x4 acc[4][4] = {};
  gemm_core(A, W, brow, bcol, tid, wm, wn, l15, l4, Asm, Bsm, acc);

  const int r0 = brow + wm + l4 * 4;
  const int c0 = bcol + wn + l15;
  if (seg < 2) {
    bf16* C = seg == 0 ? Qws : Kws;
    const float cs = seg == 0 ? qscale : 1.0f;
#pragma unroll
    for (int n = 0; n < 4; ++n) {
      const float bvv = bias[c0 + n * 16];
#pragma unroll
      for (int m = 0; m < 4; ++m)
#pragma unroll
        for (int r = 0; r < 4; ++r)
          C[(size_t)(r0 + m * 16 + r) * 1024 + (c0 + n * 16)] =
              (bf16)((acc[m][n][r] + bvv) * cs);
    }
  } else {
    // Vt[b*1024 + col][s] = V[row][col]; rows r=0..3 are s-consecutive.
#pragma unroll
    for (int n = 0; n < 4; ++n) {
      const float bvv = bias[c0 + n * 16];
      const int col = c0 + n * 16;
#pragma unroll
      for (int m = 0; m < 4; ++m) {
        const int row = r0 + m * 16;
        const int bq_ = row >> 11;
        const int srow = row & 2047;
        uint2 w;
        w.x = cvt_pk_bf16(acc[m][n][0] + bvv, acc[m][n][1] + bvv);
        w.y = cvt_pk_bf16(acc[m][n][2] + bvv, acc[m][n][3] + bvv);
        *reinterpret_cast<uint2*>(
            &Vt[(size_t)(bq_ * 1024 + col) * 2048 + srow]) = w;
      }
    }
  }
}

// Output projection GEMM (bf16 ctx @ fp32 wo^T + bo -> fp32 out).
__global__ __launch_bounds__(256, 2) void out_gemm_kernel(
    const bf16* __restrict__ A, const float* __restrict__ W,
    const float* __restrict__ bias, float* __restrict__ C) {
  __shared__ bf16 Asm[2][128 * 32];
  __shared__ bf16 Bsm[2][128 * 32];
  const int tid = threadIdx.x;
  const int lane = tid & 63;
  const int wid = tid >> 6;
  const int l15 = lane & 15;
  const int l4 = lane >> 4;
  const int bid = xcd_swizzle(blockIdx.x, 512);
  const int brow = (bid >> 3) << 7;
  const int bcol = (bid & 7) << 7;
  const int wm = (wid >> 1) << 6;
  const int wn = (wid & 1) << 6;

  f32x4 acc[4][4] = {};
  gemm_core(A, W, brow, bcol, tid, wm, wn, l15, l4, Asm, Bsm, acc);

  const int r0 = brow + wm + l4 * 4;
  const int c0 = bcol + wn + l15;
#pragma unroll
  for (int n = 0; n < 4; ++n) {
    const float bvv = bias[c0 + n * 16];
#pragma unroll
    for (int m = 0; m < 4; ++m)
#pragma unroll
      for (int r = 0; r < 4; ++r)
        C[(size_t)(r0 + m * 16 + r) * 1024 + (c0 + n * 16)] =
            acc[m][n][r] + bvv;
  }
}

// Standalone tiled-mask prep (no LDS -> full occupancy).
// M2[((b*32+t)*2048+q)*64 + h5*32 + s*16 + g*4 + r]
//   = bf16( mask[b][q][t*64 + 32s + 16(g>>1) + 4(g&1) + 8h5 + r] * log2e )
__global__ __launch_bounds__(256) void prep_mask_kernel(
    const float* __restrict__ mask, bf16* __restrict__ M2) {
  const float LOG2E = 1.44269504088896f;
  const int T0 = blockIdx.x * 256 + threadIdx.x;
#pragma unroll
  for (int i = 0; i < 4; ++i) {
    const int O = T0 + i * 524288;
    const int a = O & 3;
    const int h5 = (O >> 2) & 1;
    const int q = (O >> 3) & 2047;
    const int t = (O >> 14) & 31;
    const int b = O >> 19;
    const float* src = mask + ((size_t)(b * 2048 + q)) * 2048 + t * 64 +
                       32 * (a >> 1) + 16 * (a & 1) + 8 * h5;
    const float4 x = *reinterpret_cast<const float4*>(src);
    const float4 y = *reinterpret_cast<const float4*>(src + 4);
    u32x4 w;
    w[0] = cvt_pk_bf16(x.x * LOG2E, x.y * LOG2E);
    w[1] = cvt_pk_bf16(x.z * LOG2E, x.w * LOG2E);
    w[2] = cvt_pk_bf16(y.x * LOG2E, y.y * LOG2E);
    w[3] = cvt_pk_bf16(y.z * LOG2E, y.w * LOG2E);
    *reinterpret_cast<u32x4*>(&M2[(size_t)O * 8]) = w;
  }
}

// ---------------- Flash attention: 8-wave blocks, (512,2) bounds -----------
// r18's 512-thread kernel (correctness-proven) with launch_bounds (512,2):
// VGPR cap 256 >> natural ~90 -> no spill (r18's only failure was the (512,4)
// cap=128 -> 64-reg spill). Grid 512 = 2 blocks/CU x 8 waves = 4 waves/SIMD
// (2x r21's TLP); K/V staged once per 256 q. If attn stays ~125us at 4/SIMD,
// it is definitively DS-bandwidth-bound -> next step is the no-LDS
// fragment-direct layout.
__global__ __launch_bounds__(512, 2) void attn_kernel(
    const bf16* __restrict__ Q, const bf16* __restrict__ Kt,
    const bf16* __restrict__ Vt, const bf16* __restrict__ M2,
    bf16* __restrict__ ctx) {
  __shared__ bf16 Ksm[2][64 * 64];
  __shared__ bf16 Vsm[2][64 * 64];
  const int lid = xcd_swizzle(blockIdx.x, 512);
  const int h = lid & 15;
  const int qb = (lid >> 4) & 7;
  const int b = lid >> 7;
  const int tid = threadIdx.x;
  const int lane = tid & 63;
  const int wid = tid >> 6;           // 0..7
  const int l31 = lane & 31;
  const int h5 = lane >> 5;
  const int qbase = qb * 256 + wid * 32;

  // Q B-frags: qf[c] = Q[qbase+l31][16c + 8h5 + j] (pre-scaled by log2e/8)
  bf16x8 qf[4];
#pragma unroll
  for (int c = 0; c < 4; ++c)
    qf[c] = *reinterpret_cast<const bf16x8*>(
        &Q[(size_t)(b * 2048 + qbase + l31) * 1024 + h * 64 + c * 16 + h5 * 8]);

  f32x16 o[2] = {};  // D rows q=(reg&3)+8*(reg>>2)+4h5, col dsub*32+l31
  float lrow = 0.f;

  const bf16* Kb = Kt + (size_t)b * 2048 * 1024 + h * 64;
  const bf16* Vb = Vt + (size_t)(b * 16 + h) * 64 * 2048;

  // Staging: one 16B chunk per thread (512 x 8 elem = 64x64 tile).
  // K source row = pi(dest row) = swap bits 2,3.
  const int row_ = tid >> 3, lin_ = (tid & 7) ^ (row_ & 7);
  const int prow = (row_ & 51) | ((row_ & 4) << 1) | ((row_ & 8) >> 1);
  const bf16* kga = Kb + (size_t)prow * 1024 + lin_ * 8;
  const bf16* vga = Vb + (size_t)row_ * 2048 + lin_ * 8;
  // Tiled mask: lane's 32 bf16/tile at one contiguous 64B block.
  const bf16* mp =
      M2 + ((size_t)(b * 32) * 2048 + qbase + l31) * 64 + h5 * 32;

  auto stage = [&](int p) {  // 2 vmem ops/thread
    gload_lds16(kga, &Ksm[p][tid * 8]);
    gload_lds16(vga, &Vsm[p][tid * 8]);
    kga += 64 * 1024;  // next 64 k-rows
    vga += 64;         // next 64 k-cols
  };
  u32x4 mA[4], mB[4];  // two named mask sets: 16 words = 32 bf16
  auto load_mask = [&](u32x4(&mr)[4]) {  // 4 vmem ops, contiguous 64B
#pragma unroll
    for (int i = 0; i < 4; ++i)
      mr[i] = *reinterpret_cast<const u32x4*>(mp + i * 8);
    mp += 2048 * 64;  // next tile
  };

  auto tile_compute = [&](int p, u32x4(&mr)[4]) {
    // sf init = bf16 mask (already x log2e) -> f32: 2 VALU per word.
    f32x16 sf[2];
#pragma unroll
    for (int w = 0; w < 16; ++w) {
      const unsigned word = mr[w >> 2][w & 3];
      const int s = w >> 3;
      const int base = ((w >> 1) & 3) * 4 + (w & 1) * 2;
      sf[s][base + 0] = __builtin_bit_cast(float, word << 16);
      sf[s][base + 1] = __builtin_bit_cast(float, word & 0xffff0000u);
    }

    __builtin_amdgcn_s_setprio(1);
#pragma unroll
    for (int s = 0; s < 2; ++s) {
#pragma unroll
      for (int c = 0; c < 4; ++c) {
        const int row = s * 32 + l31;
        const int slot = (2 * c + h5) ^ (row & 7);
        const bf16x8 kf =
            *reinterpret_cast<const bf16x8*>(&Ksm[p][row * 64 + slot * 8]);
        sf[s] = MFMA32(kf, qf[c], sf[s]);
      }
    }
    __builtin_amdgcn_s_setprio(0);

    // P = exp2(sf) -> packed bf16 pairs (raw v_exp + v_cvt_pk, lane-local)
    unsigned pk[2][4][2];
#pragma unroll
    for (int s = 0; s < 2; ++s) {
#pragma unroll
      for (int g = 0; g < 4; ++g) {
        const float p0 = fast_exp2(sf[s][g * 4 + 0]);
        const float p1 = fast_exp2(sf[s][g * 4 + 1]);
        const float p2 = fast_exp2(sf[s][g * 4 + 2]);
        const float p3 = fast_exp2(sf[s][g * 4 + 3]);
        lrow += (p0 + p1) + (p2 + p3);
        pk[s][g][0] = cvt_pk_bf16(p0, p1);
        pk[s][g][1] = cvt_pk_bf16(p2, p3);
      }
    }

    // PV: chunk c's A-frag = 4 lane-local u32s (compile-time indices).
    __builtin_amdgcn_s_setprio(1);
#pragma unroll
    for (int c = 0; c < 4; ++c) {
      const int s = c >> 1;
      const int g0 = 2 * (c & 1);
      const u32x4 uu = {pk[s][g0][0], pk[s][g0][1], pk[s][g0 + 1][0],
                        pk[s][g0 + 1][1]};
      const bf16x8 pa = __builtin_bit_cast(bf16x8, uu);
#pragma unroll
      for (int dsub = 0; dsub < 2; ++dsub) {
        const int row = dsub * 32 + l31;
        const int slot = (2 * c + h5) ^ (row & 7);
        const bf16x8 vf =
            *reinterpret_cast<const bf16x8*>(&Vsm[p][row * 64 + slot * 8]);
        o[dsub] = MFMA32(pa, vf, o[dsub]);
      }
    }
    __builtin_amdgcn_s_setprio(0);
  };

  // Prologue: stage tile 0 -> buf0, mask tile 0 -> mA (6 vmem in flight).
  stage(0);
  load_mask(mA);

  for (int t = 0; t < 32; t += 2) {
    // ---- even tile t (buf0, mA) ----
    if (t + 1 < 32) {
      stage(1);          // buf1's last readers passed the previous barrier
      load_mask(mB);
      asm volatile("s_waitcnt vmcnt(6)" ::: "memory");  // stage(t)+mask(t) done
    } else {
      asm volatile("s_waitcnt vmcnt(0)" ::: "memory");
    }
    __builtin_amdgcn_s_barrier();        // publish buf0
    __builtin_amdgcn_sched_barrier(0);
    tile_compute(0, mA);
    __builtin_amdgcn_s_barrier();        // read-protect buf0
    // ---- odd tile t+1 (buf1, mB) ----
    if (t + 2 < 32) {
      stage(0);
      load_mask(mA);
      asm volatile("s_waitcnt vmcnt(6)" ::: "memory");  // stage(t+1)+mask(t+1)
    } else {
      asm volatile("s_waitcnt vmcnt(0)" ::: "memory");
    }
    __builtin_amdgcn_s_barrier();        // publish buf1
    __builtin_amdgcn_sched_barrier(0);
    tile_compute(1, mB);
    __builtin_amdgcn_s_barrier();        // read-protect buf1
  }

  // Partner lane (l^32) holds the other half of each row's sum.
  lrow += __shfl_xor(lrow, 32, 64);
  const float linv = __builtin_amdgcn_rcpf(lrow);
#pragma unroll
  for (int reg = 0; reg < 16; ++reg) {
    const int qr = (reg & 3) + 8 * (reg >> 2) + 4 * h5;
    const float li = __shfl(linv, qr, 64);
    const int q = qbase + qr;
#pragma unroll
    for (int dsub = 0; dsub < 2; ++dsub) {
      ctx[(size_t)(b * 2048 + q) * 1024 + h * 64 + dsub * 32 + l31] =
          (bf16)(o[dsub][reg] * li);
    }
  }
}

extern "C" void kernel_launch(void* const* d_in, const int* in_sizes, int n_in,
                              void* d_out, int out_size, void* d_ws,
                              size_t ws_size, hipStream_t stream) {
  const float* key = (const float*)d_in[0];
  const float* query = (const float*)d_in[1];
  const float* value = (const float*)d_in[2];
  const float* mask = (const float*)d_in[3];
  const float* wq = (const float*)d_in[4];
  const float* bq = (const float*)d_in[5];
  const float* wk = (const float*)d_in[6];
  const float* bk = (const float*)d_in[7];
  const float* wv = (const float*)d_in[8];
  const float* bv = (const float*)d_in[9];
  const float* wo = (const float*)d_in[10];
  const float* bo = (const float*)d_in[11];
  float* out = (float*)d_out;

  const size_t NBSH = (size_t)4 * 2048 * 1024;
  bf16* Qws = (bf16*)d_ws;     // Q (pre-scaled by log2e/8), later ctx in place
  bf16* Kws = Qws + NBSH;
  bf16* Vt = Kws + NBSH;       // total ws use: 50.3 MB
  bf16* M2 = (bf16*)d_out;     // tiled bf16 mask*log2e in d_out (33.5 MB,
                               // dead until out_gemm overwrites it)

  prep_mask_kernel<<<2048, dim3(256), 0, stream>>>(mask, M2);
  qkv_gemm_kernel<<<1536, dim3(256), 0, stream>>>(query, key, value, wq, wk,
                                                  wv, bq, bk, bv, Qws, Kws, Vt,
                                                  0.18033688011112f);
  attn_kernel<<<512, dim3(512), 0, stream>>>(Qws, Kws, Vt, M2, Qws);
  out_gemm_kernel<<<512, dim3(256), 0, stream>>>(Qws, wo, bo, out);
}

// Round 23
// 258.287 us; speedup vs baseline: 1.0595x; 1.0595x over previous
//
#include <hip/hip_runtime.h>
#include <hip/hip_bf16.h>

typedef __bf16 bf16;
typedef __bf16 bf16x4 __attribute__((ext_vector_type(4)));
typedef __bf16 bf16x8 __attribute__((ext_vector_type(8)));
typedef float f32x4 __attribute__((ext_vector_type(4)));
typedef float f32x16 __attribute__((ext_vector_type(16)));
typedef unsigned u32x4 __attribute__((ext_vector_type(4)));

#define MFMA16(a, b, c) __builtin_amdgcn_mfma_f32_16x16x32_bf16((a), (b), (c), 0, 0, 0)
#define MFMA32(a, b, c) __builtin_amdgcn_mfma_f32_32x32x16_bf16((a), (b), (c), 0, 0, 0)

// XCD-chunked block swizzle (nblk % 8 == 0): each XCD gets a contiguous chunk.
__device__ __forceinline__ int xcd_swizzle(int bid, int nblk) {
  const int per = nblk >> 3;
  return (bid & 7) * per + (bid >> 3);
}

__device__ __forceinline__ void gload_lds16(const bf16* g, bf16* lds) {
  __builtin_amdgcn_global_load_lds(
      (const __attribute__((address_space(1))) void*)g,
      (__attribute__((address_space(3))) void*)lds, 16, 0, 0);
}

// Raw hardware exp2 (1 trans instr). Verified correct r18-r22.
__device__ __forceinline__ float fast_exp2(float x) {
  float r;
  asm("v_exp_f32 %0, %1\n\ts_nop 1" : "=v"(r) : "v"(x));
  return r;
}

// Packed f32x2 -> bf16x2 convert (1 instr). Verified correct r18-r22.
__device__ __forceinline__ unsigned cvt_pk_bf16(float lo, float hi) {
  unsigned r;
  asm("v_cvt_pk_bf16_f32 %0, %1, %2" : "=v"(r) : "v"(lo), "v"(hi));
  return r;
}

// ---------------- GEMM machinery (128x128 tile, BK=32, 1-barrier) ----------
// BK=32: LDS 32KB -> 4 blocks/CU (r22: qkv dropped below the attn/top-5 line).
template <typename T> struct StageRegs;
template <> struct StageRegs<float> { float4 lo[2], hi[2]; };
template <> struct StageRegs<bf16> { bf16x8 v[2]; };

template <typename T>
__device__ __forceinline__ void stage_issue(StageRegs<T>& r, const T* base,
                                            int brc, int k0, int tid) {
#pragma unroll
  for (int i = 0; i < 2; ++i) {
    const int c = i * 256 + tid;     // 512 chunks of 8 elems = 128x32
    const int row = c >> 2, lin = c & 3;
    const T* p = base + (size_t)(brc + row) * 1024 + k0 + lin * 8;
    if constexpr (sizeof(T) == 4) {
      r.lo[i] = *reinterpret_cast<const float4*>(p);
      r.hi[i] = *reinterpret_cast<const float4*>(p + 4);
    } else {
      r.v[i] = *reinterpret_cast<const bf16x8*>(p);
    }
  }
}

template <typename T>
__device__ __forceinline__ void stage_write(const StageRegs<T>& r, bf16* sm,
                                            int tid) {
#pragma unroll
  for (int i = 0; i < 2; ++i) {
    const int c = i * 256 + tid;
    const int row = c >> 2, lin = c & 3;
    const int slot = lin ^ (row & 3);
    if constexpr (sizeof(T) == 4) {
      const float4 a = r.lo[i], b = r.hi[i];
      u32x4 w;
      w[0] = cvt_pk_bf16(a.x, a.y);
      w[1] = cvt_pk_bf16(a.z, a.w);
      w[2] = cvt_pk_bf16(b.x, b.y);
      w[3] = cvt_pk_bf16(b.z, b.w);
      *reinterpret_cast<u32x4*>(sm + row * 32 + slot * 8) = w;
    } else {
      *reinterpret_cast<bf16x8*>(sm + row * 32 + slot * 8) = r.v[i];
    }
  }
}

// Main loop: 32 K-tiles of 32; ONE barrier/tile; stage_issue(t+1) after the
// barrier so loads fly under compute(t). Race-safe (r20-r22 verified form).
template <typename TA>
__device__ __forceinline__ void gemm_core(const TA* A, const float* W,
                                          int brow, int bcol, int tid, int wm,
                                          int wn, int l15, int l4,
                                          bf16 (*Asm)[4096], bf16 (*Bsm)[4096],
                                          f32x4 (&acc)[4][4]) {
  StageRegs<TA> ra;
  StageRegs<float> rb;
  stage_issue(ra, A, brow, 0, tid);
  stage_issue(rb, W, bcol, 0, tid);
  int p = 0;
  for (int t = 0; t < 32; ++t) {
    stage_write(ra, Asm[p], tid);   // compiler waits vmcnt for ra/rb here
    stage_write(rb, Bsm[p], tid);
    __syncthreads();                // publish buffer p
    if (t + 1 < 32) {
      stage_issue(ra, A, brow, (t + 1) << 5, tid);  // fly under compute
      stage_issue(rb, W, bcol, (t + 1) << 5, tid);
    }
    bf16x8 af[4], bfr[4];
#pragma unroll
    for (int m = 0; m < 4; ++m) {
      const int row = wm + m * 16 + l15;
      const int slot = l4 ^ (row & 3);
      af[m] = *reinterpret_cast<const bf16x8*>(Asm[p] + row * 32 + slot * 8);
    }
#pragma unroll
    for (int n = 0; n < 4; ++n) {
      const int row = wn + n * 16 + l15;
      const int slot = l4 ^ (row & 3);
      bfr[n] = *reinterpret_cast<const bf16x8*>(Bsm[p] + row * 32 + slot * 8);
    }
    __builtin_amdgcn_s_setprio(1);
#pragma unroll
    for (int m = 0; m < 4; ++m)
#pragma unroll
      for (int n = 0; n < 4; ++n)
        acc[m][n] = MFMA16(af[m], bfr[n], acc[m][n]);
    __builtin_amdgcn_s_setprio(0);
    p ^= 1;
  }
}

// Fused QKV projection. seg 0 -> Qws (x log2e/8), seg 1 -> Kws,
// seg 2 -> Vt written TRANSPOSED.
__global__ __launch_bounds__(256, 2) void qkv_gemm_kernel(
    const float* __restrict__ query, const float* __restrict__ key,
    const float* __restrict__ value, const float* __restrict__ wq,
    const float* __restrict__ wk, const float* __restrict__ wv,
    const float* __restrict__ bq, const float* __restrict__ bk,
    const float* __restrict__ bv, bf16* __restrict__ Qws,
    bf16* __restrict__ Kws, bf16* __restrict__ Vt, float qscale) {
  __shared__ bf16 Asm[2][128 * 32];
  __shared__ bf16 Bsm[2][128 * 32];
  const int tid = threadIdx.x;
  const int lane = tid & 63;
  const int wid = tid >> 6;
  const int l15 = lane & 15;
  const int l4 = lane >> 4;
  const int bid = xcd_swizzle(blockIdx.x, 1536);
  const int seg = bid / 512;
  const int inner = bid % 512;
  const int brow = (inner >> 3) << 7;
  const int bcol = (inner & 7) << 7;
  const int wm = (wid >> 1) << 6;
  const int wn = (wid & 1) << 6;

  const float* A = seg == 0 ? query : (seg == 1 ? key : value);
  const float* W = seg == 0 ? wq : (seg == 1 ? wk : wv);
  const float* bias = seg == 0 ? bq : (seg == 1 ? bk : bv);

  f32x4 acc[4][4] = {};
  gemm_core(A, W, brow, bcol, tid, wm, wn, l15, l4, Asm, Bsm, acc);

  const int r0 = brow + wm + l4 * 4;
  const int c0 = bcol + wn + l15;
  if (seg < 2) {
    bf16* C = seg == 0 ? Qws : Kws;
    const float cs = seg == 0 ? qscale : 1.0f;
#pragma unroll
    for (int n = 0; n < 4; ++n) {
      const float bvv = bias[c0 + n * 16];
#pragma unroll
      for (int m = 0; m < 4; ++m)
#pragma unroll
        for (int r = 0; r < 4; ++r)
          C[(size_t)(r0 + m * 16 + r) * 1024 + (c0 + n * 16)] =
              (bf16)((acc[m][n][r] + bvv) * cs);
    }
  } else {
    // Vt[b*1024 + col][s] = V[row][col]; rows r=0..3 are s-consecutive.
#pragma unroll
    for (int n = 0; n < 4; ++n) {
      const float bvv = bias[c0 + n * 16];
      const int col = c0 + n * 16;
#pragma unroll
      for (int m = 0; m < 4; ++m) {
        const int row = r0 + m * 16;
        const int bq_ = row >> 11;
        const int srow = row & 2047;
        uint2 w;
        w.x = cvt_pk_bf16(acc[m][n][0] + bvv, acc[m][n][1] + bvv);
        w.y = cvt_pk_bf16(acc[m][n][2] + bvv, acc[m][n][3] + bvv);
        *reinterpret_cast<uint2*>(
            &Vt[(size_t)(bq_ * 1024 + col) * 2048 + srow]) = w;
      }
    }
  }
}

// Output projection GEMM (bf16 ctx @ fp32 wo^T + bo -> fp32 out).
__global__ __launch_bounds__(256, 2) void out_gemm_kernel(
    const bf16* __restrict__ A, const float* __restrict__ W,
    const float* __restrict__ bias, float* __restrict__ C) {
  __shared__ bf16 Asm[2][128 * 32];
  __shared__ bf16 Bsm[2][128 * 32];
  const int tid = threadIdx.x;
  const int lane = tid & 63;
  const int wid = tid >> 6;
  const int l15 = lane & 15;
  const int l4 = lane >> 4;
  const int bid = xcd_swizzle(blockIdx.x, 512);
  const int brow = (bid >> 3) << 7;
  const int bcol = (bid & 7) << 7;
  const int wm = (wid >> 1) << 6;
  const int wn = (wid & 1) << 6;

  f32x4 acc[4][4] = {};
  gemm_core(A, W, brow, bcol, tid, wm, wn, l15, l4, Asm, Bsm, acc);

  const int r0 = brow + wm + l4 * 4;
  const int c0 = bcol + wn + l15;
#pragma unroll
  for (int n = 0; n < 4; ++n) {
    const float bvv = bias[c0 + n * 16];
#pragma unroll
    for (int m = 0; m < 4; ++m)
#pragma unroll
      for (int r = 0; r < 4; ++r)
        C[(size_t)(r0 + m * 16 + r) * 1024 + (c0 + n * 16)] =
            acc[m][n][r] + bvv;
  }
}

// Standalone tiled-mask prep (no LDS -> full occupancy).
// M2[((b*32+t)*2048+q)*64 + h5*32 + s*16 + g*4 + r]
//   = bf16( mask[b][q][t*64 + 32s + 16(g>>1) + 4(g&1) + 8h5 + r] * log2e )
__global__ __launch_bounds__(256) void prep_mask_kernel(
    const float* __restrict__ mask, bf16* __restrict__ M2) {
  const float LOG2E = 1.44269504088896f;
  const int T0 = blockIdx.x * 256 + threadIdx.x;
#pragma unroll
  for (int i = 0; i < 4; ++i) {
    const int O = T0 + i * 524288;
    const int a = O & 3;
    const int h5 = (O >> 2) & 1;
    const int q = (O >> 3) & 2047;
    const int t = (O >> 14) & 31;
    const int b = O >> 19;
    const float* src = mask + ((size_t)(b * 2048 + q)) * 2048 + t * 64 +
                       32 * (a >> 1) + 16 * (a & 1) + 8 * h5;
    const float4 x = *reinterpret_cast<const float4*>(src);
    const float4 y = *reinterpret_cast<const float4*>(src + 4);
    u32x4 w;
    w[0] = cvt_pk_bf16(x.x * LOG2E, x.y * LOG2E);
    w[1] = cvt_pk_bf16(x.z * LOG2E, x.w * LOG2E);
    w[2] = cvt_pk_bf16(y.x * LOG2E, y.y * LOG2E);
    w[3] = cvt_pk_bf16(y.z * LOG2E, y.w * LOG2E);
    *reinterpret_cast<u32x4*>(&M2[(size_t)O * 8]) = w;
  }
}

// ---------------- Flash attention: r21 kernel (best measured, 129us) -------
// Block = (b, h, 128 q); 4 waves x 32 q; 2 LDS buffers (32 KB); (256,3)
// bounds (caps <=128 VGPR spill: r7/r13/r18). Counted vmcnt(8) + raw-barrier
// loop; tiled bf16 mask; pi-permuted K keeps P lane-local for PV; raw
// v_exp_f32 + v_cvt_pk_bf16_f32; Q pre-scaled by log2e/8; fixed-shift
// softmax (exact). r22's 8-wave variant regressed (148us) -> reverted.
__global__ __launch_bounds__(256, 3) void attn_kernel(
    const bf16* __restrict__ Q, const bf16* __restrict__ Kt,
    const bf16* __restrict__ Vt, const bf16* __restrict__ M2,
    bf16* __restrict__ ctx) {
  __shared__ bf16 Ksm[2][64 * 64];
  __shared__ bf16 Vsm[2][64 * 64];
  const int lid = xcd_swizzle(blockIdx.x, 1024);
  const int h = lid & 15;
  const int qb = (lid >> 4) & 15;
  const int b = lid >> 8;
  const int tid = threadIdx.x;
  const int lane = tid & 63;
  const int wid = tid >> 6;
  const int l31 = lane & 31;
  const int h5 = lane >> 5;
  const int qbase = qb * 128 + wid * 32;

  // Q B-frags: qf[c] = Q[qbase+l31][16c + 8h5 + j] (pre-scaled by log2e/8)
  bf16x8 qf[4];
#pragma unroll
  for (int c = 0; c < 4; ++c)
    qf[c] = *reinterpret_cast<const bf16x8*>(
        &Q[(size_t)(b * 2048 + qbase + l31) * 1024 + h * 64 + c * 16 + h5 * 8]);

  f32x16 o[2] = {};  // D rows q=(reg&3)+8*(reg>>2)+4h5, col dsub*32+l31
  float lrow = 0.f;

  const bf16* Kb = Kt + (size_t)b * 2048 * 1024 + h * 64;
  const bf16* Vb = Vt + (size_t)(b * 16 + h) * 64 * 2048;

  // Staging pointers. K source row = pi(dest row) = swap bits 2,3.
  const int ca = tid, cb = 256 + tid;
  const int ra_ = ca >> 3, la = (ca & 7) ^ (ra_ & 7);
  const int rb_ = cb >> 3, lb = (cb & 7) ^ (rb_ & 7);
  const int pra = (ra_ & 51) | ((ra_ & 4) << 1) | ((ra_ & 8) >> 1);
  const int prb = (rb_ & 51) | ((rb_ & 4) << 1) | ((rb_ & 8) >> 1);
  const bf16* kga = Kb + (size_t)pra * 1024 + la * 8;
  const bf16* kgb = Kb + (size_t)prb * 1024 + lb * 8;
  const bf16* vga = Vb + (size_t)ra_ * 2048 + la * 8;
  const bf16* vgb = Vb + (size_t)rb_ * 2048 + lb * 8;
  // Tiled mask: lane's 32 bf16/tile at one contiguous 64B block.
  const bf16* mp =
      M2 + ((size_t)(b * 32) * 2048 + qbase + l31) * 64 + h5 * 32;

  auto stage = [&](int p) {  // 4 vmem ops
    gload_lds16(kga, &Ksm[p][tid * 8]);
    gload_lds16(kgb, &Ksm[p][2048 + tid * 8]);
    gload_lds16(vga, &Vsm[p][tid * 8]);
    gload_lds16(vgb, &Vsm[p][2048 + tid * 8]);
    kga += 64 * 1024; kgb += 64 * 1024;
    vga += 64; vgb += 64;
  };
  u32x4 mA[4], mB[4];  // two named mask sets: 16 words = 32 bf16
  auto load_mask = [&](u32x4(&mr)[4]) {  // 4 vmem ops, contiguous 64B
#pragma unroll
    for (int i = 0; i < 4; ++i)
      mr[i] = *reinterpret_cast<const u32x4*>(mp + i * 8);
    mp += 2048 * 64;  // next tile
  };

  auto tile_compute = [&](int p, u32x4(&mr)[4]) {
    // sf init = bf16 mask (already x log2e) -> f32: 2 VALU per word.
    f32x16 sf[2];
#pragma unroll
    for (int w = 0; w < 16; ++w) {
      const unsigned word = mr[w >> 2][w & 3];
      const int s = w >> 3;
      const int base = ((w >> 1) & 3) * 4 + (w & 1) * 2;
      sf[s][base + 0] = __builtin_bit_cast(float, word << 16);
      sf[s][base + 1] = __builtin_bit_cast(float, word & 0xffff0000u);
    }

    __builtin_amdgcn_s_setprio(1);
#pragma unroll
    for (int s = 0; s < 2; ++s) {
#pragma unroll
      for (int c = 0; c < 4; ++c) {
        const int row = s * 32 + l31;
        const int slot = (2 * c + h5) ^ (row & 7);
        const bf16x8 kf =
            *reinterpret_cast<const bf16x8*>(&Ksm[p][row * 64 + slot * 8]);
        sf[s] = MFMA32(kf, qf[c], sf[s]);
      }
    }
    __builtin_amdgcn_s_setprio(0);

    // P = exp2(sf) -> packed bf16 pairs (raw v_exp + v_cvt_pk, lane-local)
    unsigned pk[2][4][2];
#pragma unroll
    for (int s = 0; s < 2; ++s) {
#pragma unroll
      for (int g = 0; g < 4; ++g) {
        const float p0 = fast_exp2(sf[s][g * 4 + 0]);
        const float p1 = fast_exp2(sf[s][g * 4 + 1]);
        const float p2 = fast_exp2(sf[s][g * 4 + 2]);
        const float p3 = fast_exp2(sf[s][g * 4 + 3]);
        lrow += (p0 + p1) + (p2 + p3);
        pk[s][g][0] = cvt_pk_bf16(p0, p1);
        pk[s][g][1] = cvt_pk_bf16(p2, p3);
      }
    }

    // PV: chunk c's A-frag = 4 lane-local u32s (compile-time indices).
    __builtin_amdgcn_s_setprio(1);
#pragma unroll
    for (int c = 0; c < 4; ++c) {
      const int s = c >> 1;
      const int g0 = 2 * (c & 1);
      const u32x4 uu = {pk[s][g0][0], pk[s][g0][1], pk[s][g0 + 1][0],
                        pk[s][g0 + 1][1]};
      const bf16x8 pa = __builtin_bit_cast(bf16x8, uu);
#pragma unroll
      for (int dsub = 0; dsub < 2; ++dsub) {
        const int row = dsub * 32 + l31;
        const int slot = (2 * c + h5) ^ (row & 7);
        const bf16x8 vf =
            *reinterpret_cast<const bf16x8*>(&Vsm[p][row * 64 + slot * 8]);
        o[dsub] = MFMA32(pa, vf, o[dsub]);
      }
    }
    __builtin_amdgcn_s_setprio(0);
  };

  // Prologue: stage tile 0 -> buf0, mask tile 0 -> mA (8 vmem in flight).
  stage(0);
  load_mask(mA);

  for (int t = 0; t < 32; t += 2) {
    // ---- even tile t (buf0, mA) ----
    if (t + 1 < 32) {
      stage(1);          // buf1's last readers passed the previous barrier
      load_mask(mB);
      asm volatile("s_waitcnt vmcnt(8)" ::: "memory");  // stage(t)+mask(t) done
    } else {
      asm volatile("s_waitcnt vmcnt(0)" ::: "memory");
    }
    __builtin_amdgcn_s_barrier();        // publish buf0
    __builtin_amdgcn_sched_barrier(0);
    tile_compute(0, mA);
    __builtin_amdgcn_s_barrier();        // read-protect buf0
    // ---- odd tile t+1 (buf1, mB) ----
    if (t + 2 < 32) {
      stage(0);
      load_mask(mA);
      asm volatile("s_waitcnt vmcnt(8)" ::: "memory");  // stage(t+1)+mask(t+1)
    } else {
      asm volatile("s_waitcnt vmcnt(0)" ::: "memory");
    }
    __builtin_amdgcn_s_barrier();        // publish buf1
    __builtin_amdgcn_sched_barrier(0);
    tile_compute(1, mB);
    __builtin_amdgcn_s_barrier();        // read-protect buf1
  }

  // Partner lane (l^32) holds the other half of each row's sum.
  lrow += __shfl_xor(lrow, 32, 64);
  const float linv = __builtin_amdgcn_rcpf(lrow);
#pragma unroll
  for (int reg = 0; reg < 16; ++reg) {
    const int qr = (reg & 3) + 8 * (reg >> 2) + 4 * h5;
    const float li = __shfl(linv, qr, 64);
    const int q = qbase + qr;
#pragma unroll
    for (int dsub = 0; dsub < 2; ++dsub) {
      ctx[(size_t)(b * 2048 + q) * 1024 + h * 64 + dsub * 32 + l31] =
          (bf16)(o[dsub][reg] * li);
    }
  }
}

extern "C" void kernel_launch(void* const* d_in, const int* in_sizes, int n_in,
                              void* d_out, int out_size, void* d_ws,
                              size_t ws_size, hipStream_t stream) {
  const float* key = (const float*)d_in[0];
  const float* query = (const float*)d_in[1];
  const float* value = (const float*)d_in[2];
  const float* mask = (const float*)d_in[3];
  const float* wq = (const float*)d_in[4];
  const float* bq = (const float*)d_in[5];
  const float* wk = (const float*)d_in[6];
  const float* bk = (const float*)d_in[7];
  const float* wv = (const float*)d_in[8];
  const float* bv = (const float*)d_in[9];
  const float* wo = (const float*)d_in[10];
  const float* bo = (const float*)d_in[11];
  float* out = (float*)d_out;

  const size_t NBSH = (size_t)4 * 2048 * 1024;
  bf16* Qws = (bf16*)d_ws;     // Q (pre-scaled by log2e/8), later ctx in place
  bf16* Kws = Qws + NBSH;
  bf16* Vt = Kws + NBSH;       // total ws use: 50.3 MB
  bf16* M2 = (bf16*)d_out;     // tiled bf16 mask*log2e in d_out (33.5 MB,
                               // dead until out_gemm overwrites it)

  prep_mask_kernel<<<2048, dim3(256), 0, stream>>>(mask, M2);
  qkv_gemm_kernel<<<1536, dim3(256), 0, stream>>>(query, key, value, wq, wk,
                                                  wv, bq, bk, bv, Qws, Kws, Vt,
                                                  0.18033688011112f);
  attn_kernel<<<1024, dim3(256), 0, stream>>>(Qws, Kws, Vt, M2, Qws);
  out_gemm_kernel<<<512, dim3(256), 0, stream>>>(Qws, wo, bo, out);
}